// Round 2
// baseline (148.469 us; speedup 1.0000x reference)
//
#include <hip/hip_runtime.h>
#include <hip/hip_bf16.h>

// Problem: B=32, L=512, D=1024, R=128
//   t = batch(16384x1024) @ proj(1024x128)          [bf16 MFMA, fp32 acc]
//   d[b,i,j] = ||t_i||^2 + ||t_j||^2 - 2 t_i.t_j,  clamp >= 0
//
// ws layout: projT bf16 [128][1024] (256KB) | t bf16 [16384][128] (4MB) | sqn f32 [16384] (64KB)
//
// R2 design: barrier-free K-loops. B operands read directly from L2-resident
// global (projT 256KB / t_b 128KB) so no LDS staging and no s_barrier vmcnt(0)
// drain; compiler software-pipelines loads with fine-grained vmcnt. dist_k
// computes the transposed tile so stores are float4 (j-contiguous per lane).

typedef __attribute__((ext_vector_type(8))) short bf16x8;
typedef __attribute__((ext_vector_type(4))) float f32x4;

__device__ __forceinline__ unsigned short f2bf(float f) {
    unsigned u = __float_as_uint(f);
    unsigned r = (u + 0x7fffu + ((u >> 16) & 1u)) >> 16;   // RNE
    return (unsigned short)r;
}
__device__ __forceinline__ float bf2f(unsigned short h) {
    return __uint_as_float(((unsigned)h) << 16);
}
__device__ __forceinline__ bf16x8 pack8(float4 x, float4 y) {
    bf16x8 r;
    r[0] = (short)f2bf(x.x); r[1] = (short)f2bf(x.y);
    r[2] = (short)f2bf(x.z); r[3] = (short)f2bf(x.w);
    r[4] = (short)f2bf(y.x); r[5] = (short)f2bf(y.y);
    r[6] = (short)f2bf(y.z); r[7] = (short)f2bf(y.w);
    return r;
}

// ---------------- kernel 0: proj (1024x128 f32) -> projT (128x1024 bf16) ----------------
__global__ __launch_bounds__(256) void transpose_proj(const float* __restrict__ proj,
                                                      unsigned short* __restrict__ projT) {
    __shared__ unsigned short TsT[128][40];   // [r][k_local], pad 32->40
    const int k0 = blockIdx.x * 32;           // 32 blocks cover D=1024
    const int t = threadIdx.x;
    const int kl = t >> 3;                    // 0..31
    const int seg = t & 7;                    // 0..7
    const float* src = proj + (k0 + kl) * 128 + seg * 16;
#pragma unroll
    for (int i = 0; i < 4; ++i) {
        float4 v = *(const float4*)(src + 4 * i);
        int c = seg * 16 + 4 * i;
        TsT[c + 0][kl] = f2bf(v.x);
        TsT[c + 1][kl] = f2bf(v.y);
        TsT[c + 2][kl] = f2bf(v.z);
        TsT[c + 3][kl] = f2bf(v.w);
    }
    __syncthreads();
    const int r = t >> 1, h = t & 1;
#pragma unroll
    for (int i = 0; i < 2; ++i) {
        *(uint4*)(projT + r * 1024 + k0 + h * 16 + 8 * i) =
            *(const uint4*)&TsT[r][h * 16 + 8 * i];
    }
}

// ---------------- kernel 1: t = batch @ proj  (M=16384, N=128, K=1024) ----------------
// grid 512 (M-tile 32), block 256 = 4 waves arranged 2(M) x 2(N).
// Barrier-free: A from global fp32 (read-once), B fragments from L2-resident
// projT directly into registers. Single __syncthreads only in the sqn epilogue.
__global__ __launch_bounds__(256) void gemm_t(const float* __restrict__ batch,
                                              const unsigned short* __restrict__ projT,
                                              unsigned short* __restrict__ tOut,
                                              float* __restrict__ sqn) {
    __shared__ float sqpart[2][2][16];

    const int t = threadIdx.x;
    const int wave = t >> 6, lane = t & 63;
    const int wm = wave >> 1, wn = wave & 1;
    const int quad = lane >> 4, l15 = lane & 15;
    const int m0 = blockIdx.x * 32;

    f32x4 acc[4] = {};                        // cols wn*64 + fn*16 + l15

    const float* aptr = batch + (m0 + wm * 16 + l15) * 1024 + quad * 8;
    // B fragment base pointers (per fn), k-offset added in loop
    const unsigned short* bptr[4];
#pragma unroll
    for (int fn = 0; fn < 4; ++fn)
        bptr[fn] = projT + (wn * 64 + fn * 16 + l15) * 1024 + quad * 8;

#pragma unroll 2
    for (int kk = 0; kk < 1024; kk += 64) {
        float4 a0 = *(const float4*)(aptr + kk);
        float4 a1 = *(const float4*)(aptr + kk + 4);
        float4 a2 = *(const float4*)(aptr + kk + 32);
        float4 a3 = *(const float4*)(aptr + kk + 36);
        bf16x8 b0[4], b1[4];
#pragma unroll
        for (int fn = 0; fn < 4; ++fn) {
            b0[fn] = *(const bf16x8*)(bptr[fn] + kk);
            b1[fn] = *(const bf16x8*)(bptr[fn] + kk + 32);
        }
        bf16x8 af0 = pack8(a0, a1);
        bf16x8 af1 = pack8(a2, a3);
#pragma unroll
        for (int fn = 0; fn < 4; ++fn)
            acc[fn] = __builtin_amdgcn_mfma_f32_16x16x32_bf16(af0, b0[fn], acc[fn], 0, 0, 0);
#pragma unroll
        for (int fn = 0; fn < 4; ++fn)
            acc[fn] = __builtin_amdgcn_mfma_f32_16x16x32_bf16(af1, b1[fn], acc[fn], 0, 0, 0);
    }

    // epilogue: write t (bf16), accumulate row sq-norms from ROUNDED values
    float p[4] = {0.f, 0.f, 0.f, 0.f};
#pragma unroll
    for (int fn = 0; fn < 4; ++fn) {
        int col = wn * 64 + fn * 16 + l15;
#pragma unroll
        for (int reg = 0; reg < 4; ++reg) {
            int row = m0 + wm * 16 + quad * 4 + reg;
            unsigned short hb = f2bf(acc[fn][reg]);
            tOut[row * 128 + col] = hb;
            float fv = bf2f(hb);
            p[reg] += fv * fv;
        }
    }
#pragma unroll
    for (int off = 1; off < 16; off <<= 1) {
#pragma unroll
        for (int reg = 0; reg < 4; ++reg) p[reg] += __shfl_xor(p[reg], off);
    }
    if (l15 == 0) {
#pragma unroll
        for (int reg = 0; reg < 4; ++reg) sqpart[wm][wn][quad * 4 + reg] = p[reg];
    }
    __syncthreads();
    if (t < 32) {
        int wmi = t >> 4, ridx = t & 15;
        sqn[m0 + wmi * 16 + ridx] = sqpart[wmi][0][ridx] + sqpart[wmi][1][ridx];
    }
}

// ---------------- kernel 2: d[b,i,j] = sq_i + sq_j - 2 * t_i . t_j, clamped ----------------
// grid 512 = 32 batches x (4 i-tiles x 4 j-tiles of 128). block 256 = 4 waves.
// TRANSPOSED tile: A = t_j rows (wave owns 32 j-rows), B = t_i cols (all 128,
// from L2). C[row=j_local, col=i_local] -> per-lane regs are j-consecutive ->
// float4 stores. Barrier-free, no LDS.
__global__ __launch_bounds__(256) void dist_k(const unsigned short* __restrict__ tMat,
                                              const float* __restrict__ sqn,
                                              float* __restrict__ out) {
    const int bx = blockIdx.x;
    const int b = bx >> 4, it = (bx >> 2) & 3, jt = bx & 3;
    const int i0 = it * 128, j0 = jt * 128;
    const int t = threadIdx.x;
    const int wave = t >> 6, lane = t & 63;
    const int quad = lane >> 4, l15 = lane & 15;

    // A fragments: j-rows j0 + wave*32 + fm*16 + l15
    const unsigned short* abase = tMat + (b * 512 + j0 + wave * 32 + l15) * 128 + quad * 8;
    uint4 araw[2][4];
#pragma unroll
    for (int fm = 0; fm < 2; ++fm)
#pragma unroll
        for (int ksi = 0; ksi < 4; ++ksi)
            araw[fm][ksi] = *(const uint4*)(abase + fm * 16 * 128 + ksi * 32);

    // sq-norm scalars
    const float* sqb = sqn + b * 512;
    float sqj_[2][4], sqi_[8];
#pragma unroll
    for (int fm = 0; fm < 2; ++fm)
#pragma unroll
        for (int reg = 0; reg < 4; ++reg)
            sqj_[fm][reg] = sqb[j0 + wave * 32 + fm * 16 + quad * 4 + reg];
#pragma unroll
    for (int fn = 0; fn < 8; ++fn)
        sqi_[fn] = sqb[i0 + fn * 16 + l15];

    // B fragments: i-cols i0 + fn*16 + l15, straight from L2-resident t_b
    const unsigned short* bbase = tMat + (b * 512 + i0 + l15) * 128 + quad * 8;

    f32x4 acc[2][8] = {};
#pragma unroll
    for (int ksi = 0; ksi < 4; ++ksi) {
        bf16x8 bfr[8];
#pragma unroll
        for (int fn = 0; fn < 8; ++fn)
            bfr[fn] = *(const bf16x8*)(bbase + fn * 16 * 128 + ksi * 32);
#pragma unroll
        for (int fm = 0; fm < 2; ++fm) {
            bf16x8 af = *(const bf16x8*)&araw[fm][ksi];
#pragma unroll
            for (int fn = 0; fn < 8; ++fn)
                acc[fm][fn] = __builtin_amdgcn_mfma_f32_16x16x32_bf16(af, bfr[fn], acc[fm][fn], 0, 0, 0);
        }
    }

    // epilogue: d = sq_i + sq_j - 2c, clamp, float4 stores (j-contiguous)
    float* obase = out + (size_t)b * 512 * 512;
#pragma unroll
    for (int fn = 0; fn < 8; ++fn) {
        const int i = i0 + fn * 16 + l15;
        float* orow = obase + (size_t)i * 512 + j0;
        const float si = sqi_[fn];
#pragma unroll
        for (int fm = 0; fm < 2; ++fm) {
            float4 v;
            v.x = fmaxf(si + sqj_[fm][0] - 2.0f * acc[fm][fn][0], 0.0f);
            v.y = fmaxf(si + sqj_[fm][1] - 2.0f * acc[fm][fn][1], 0.0f);
            v.z = fmaxf(si + sqj_[fm][2] - 2.0f * acc[fm][fn][2], 0.0f);
            v.w = fmaxf(si + sqj_[fm][3] - 2.0f * acc[fm][fn][3], 0.0f);
            *(float4*)(orow + wave * 32 + fm * 16 + quad * 4) = v;
        }
    }
}

extern "C" void kernel_launch(void* const* d_in, const int* in_sizes, int n_in,
                              void* d_out, int out_size, void* d_ws, size_t ws_size,
                              hipStream_t stream) {
    (void)in_sizes; (void)n_in; (void)out_size; (void)ws_size;
    const float* batch = (const float*)d_in[0];
    const float* proj  = (const float*)d_in[1];
    float* out = (float*)d_out;

    unsigned short* projT = (unsigned short*)d_ws;          // 128*1024 bf16
    unsigned short* tMat  = projT + 128 * 1024;             // 16384*128 bf16
    float* sqn = (float*)(tMat + 16384 * 128);              // 16384 f32

    hipLaunchKernelGGL(transpose_proj, dim3(32),  dim3(256), 0, stream, proj, projT);
    hipLaunchKernelGGL(gemm_t,         dim3(512), dim3(256), 0, stream, batch, projT, tMat, sqn);
    hipLaunchKernelGGL(dist_k,         dim3(512), dim3(256), 0, stream, tMat, sqn, out);
}